// Round 8
// baseline (560.911 us; speedup 1.0000x reference)
//
#include <hip/hip_runtime.h>
#include <cstdint>
#include <cstddef>

typedef __bf16 bf16_t;
typedef __attribute__((ext_vector_type(8))) __bf16 bf16x8;
typedef __attribute__((ext_vector_type(4))) __bf16 bf16x4;
typedef __attribute__((ext_vector_type(4))) float floatx4;

#define NB 32
#define NW 168
#define NM 2048
#define NHID 128
#define NBW 5376  // NB*NW

#define GLOAD_LDS16(g, l)                                          \
  __builtin_amdgcn_global_load_lds(                                \
      (const __attribute__((address_space(1))) void*)(g),          \
      (__attribute__((address_space(3))) void*)(l), 16, 0, 0)

// Prep: [0,2688): x -> XT [m][(b,w)] bf16 (transpose-cast);
// [2688,3712): L -> Lb (cast) + Ltb (transpose-cast);
// [3712,3719): W1 -> W1p [7][128][192], w>=168 zeroed.
__global__ void prep_all(const float* __restrict__ x, bf16_t* __restrict__ XT,
                         const float* __restrict__ L, bf16_t* __restrict__ Lb,
                         bf16_t* __restrict__ Ltb, const float* __restrict__ W1,
                         bf16_t* __restrict__ W1p) {
  __shared__ float tile[64][65];
  int bid = blockIdx.x;
  int t = threadIdx.x;
  if (bid < 2688) {
    int r0 = (bid >> 5) * 64, c0 = (bid & 31) * 64;  // r over NBW, c over NM
    int tr = t >> 4, tc4 = (t & 15) * 4;
#pragma unroll
    for (int p = 0; p < 4; ++p) {
      int row = p * 16 + tr;
      float4 v = *(const float4*)(x + (size_t)(r0 + row) * NM + c0 + tc4);
      tile[row][tc4 + 0] = v.x;
      tile[row][tc4 + 1] = v.y;
      tile[row][tc4 + 2] = v.z;
      tile[row][tc4 + 3] = v.w;
    }
    __syncthreads();
#pragma unroll
    for (int p = 0; p < 4; ++p) {
      int c = p * 16 + tr;
      bf16x4 o = {(bf16_t)tile[tc4 + 0][c], (bf16_t)tile[tc4 + 1][c],
                  (bf16_t)tile[tc4 + 2][c], (bf16_t)tile[tc4 + 3][c]};
      *(bf16x4*)(XT + (size_t)(c0 + c) * NBW + r0 + tc4) = o;
    }
  } else if (bid < 3712) {
    int l = bid - 2688;
    int r0 = (l >> 5) * 64, c0 = (l & 31) * 64;  // over NM x NM
    int tr = t >> 4, tc4 = (t & 15) * 4;
#pragma unroll
    for (int p = 0; p < 4; ++p) {
      int row = p * 16 + tr;
      float4 v = *(const float4*)(L + (size_t)(r0 + row) * NM + c0 + tc4);
      tile[row][tc4 + 0] = v.x;
      tile[row][tc4 + 1] = v.y;
      tile[row][tc4 + 2] = v.z;
      tile[row][tc4 + 3] = v.w;
      bf16x4 o = {(bf16_t)v.x, (bf16_t)v.y, (bf16_t)v.z, (bf16_t)v.w};
      *(bf16x4*)(Lb + (size_t)(r0 + row) * NM + c0 + tc4) = o;
    }
    __syncthreads();
#pragma unroll
    for (int p = 0; p < 4; ++p) {
      int c = p * 16 + tr;
      bf16x4 o = {(bf16_t)tile[tc4 + 0][c], (bf16_t)tile[tc4 + 1][c],
                  (bf16_t)tile[tc4 + 2][c], (bf16_t)tile[tc4 + 3][c]};
      *(bf16x4*)(Ltb + (size_t)(c0 + c) * NM + r0 + tc4) = o;
    }
  } else {
    int hop = bid - 3712;
    const float* src = W1 + (size_t)hop * NHID * NW;
    bf16_t* dst = W1p + (size_t)hop * NHID * 192;
    for (int c = t; c < 3072; c += 256) {
      int h = c / 24, kc = c % 24;
      bf16x8 o;
      if (kc < 21) {
        const float* s = src + (size_t)h * NW + kc * 8;
#pragma unroll
        for (int j = 0; j < 8; ++j) o[j] = (bf16_t)s[j];
      } else {
#pragma unroll
        for (int j = 0; j < 8; ++j) o[j] = (bf16_t)0.0f;
      }
      *(bf16x8*)(dst + (size_t)h * 192 + kc * 8) = o;
    }
  }
}

// Hop 0: out[b,m] = sum_h relu(Z0[(b*128+h)][m] + b1_0[h]) * W2_0[h] + b2_0.
// Plain store (runs before all H dispatches; covers every (b,m)).
__global__ void score0(const bf16_t* __restrict__ Z0, const float* __restrict__ b1,
                       const float* __restrict__ W2, const float* __restrict__ b2,
                       float* __restrict__ out) {
  __shared__ float sred[2][128];
  int bid = blockIdx.x;  // b*16 + mt
  int b = bid >> 4, mt = bid & 15;
  int t = threadIdx.x;
  int c = t & 127, rh = t >> 7;
  const bf16_t* base = Z0 + (size_t)b * 128 * 2048 + mt * 128 + c;
  float acc = 0.f;
  for (int h = rh; h < 128; h += 2) {
    float z = (float)base[(size_t)h * 2048];
    float v = z + b1[h];
    v = v > 0.f ? v : 0.f;
    acc += v * W2[h];
  }
  sred[rh][c] = acc;
  __syncthreads();
  if (t < 128) out[(size_t)b * NM + mt * 128 + c] = sred[0][c] + sred[1][c] + b2[0];
}

// Mixed-job dispatch kernel. Job types (block-uniform):
//  jt=0 POW:  C[m][n] = sum_k A[m,k]*Bt[n,k]  (256 blk; optional Ct transposed store)
//  jt=1 H:    H[m][(b,h)] = sum_k A[m,k]*Z[(b*128+h),k]; fused relu.W2 epilogue
//             -> atomicAdd(out[b*NM+m])  (512 blk: 16 m-tiles x 32 b)
//  jt=2 Z:    Z_hop[(b*128+h)][j] = sum_w W1p[hop][h][w]*XT[j][b*168+w]
//             (512 blk/hop: b*16 + j-tile; K=192, direct-global, W1p pad=0)
// Z ring slot = hop & 3.
template <int D>
__global__ void mega(const bf16_t* __restrict__ XT, const bf16_t* __restrict__ W1p,
                     const bf16_t* __restrict__ Lb, const bf16_t* __restrict__ Ltb,
                     bf16_t* __restrict__ L2t, bf16_t* __restrict__ L2,
                     bf16_t* __restrict__ L3, bf16_t* __restrict__ L4,
                     bf16_t* __restrict__ L5, bf16_t* __restrict__ L6,
                     bf16_t* __restrict__ Z, const float* __restrict__ b1,
                     const float* __restrict__ W2, const float* __restrict__ b2,
                     float* __restrict__ out) {
  __shared__ bf16_t As[128 * 32];
  __shared__ bf16_t Bs[128 * 32];
  __shared__ float sred[4][64];
  const size_t ZS = (size_t)4096 * 2048;
  int bid = blockIdx.x, tid = threadIdx.x;
  int lane = tid & 63, wv = tid >> 6;
  int wm = wv >> 1, wn = wv & 1;
  int quad = lane >> 4, l15 = lane & 15;

  int jt, hop = 0, lb = 0;
  const bf16_t* A = nullptr;
  const bf16_t* Bt = nullptr;
  bf16_t* C = nullptr;
  bf16_t* Ct = nullptr;
  if constexpr (D == 1) {
    if (bid < 256)       { jt = 0; lb = bid;        A = Lb; Bt = Ltb; C = L2; Ct = L2t; }
    else                 { jt = 2; int z = bid - 256;  hop = z >> 9;       lb = z & 511; }
  } else if constexpr (D == 2) {
    if (bid < 256)       { jt = 0; lb = bid;        A = L2; Bt = Ltb; C = L3; }
    else if (bid < 512)  { jt = 0; lb = bid - 256;  A = L2; Bt = L2t; C = L4; }
    else if (bid < 1024) { jt = 1; lb = bid - 512;  A = Lb; Bt = Z + 1 * ZS; hop = 1; }
    else                 { jt = 2; int z = bid - 1024; hop = 2 + (z >> 9); lb = z & 511; }
  } else if constexpr (D == 3) {
    if (bid < 256)       { jt = 0; lb = bid;        A = L3; Bt = L2t; C = L5; }
    else if (bid < 512)  { jt = 0; lb = bid - 256;  A = L4; Bt = L2t; C = L6; }
    else if (bid < 1024) { jt = 1; lb = bid - 512;  A = L2; Bt = Z + 2 * ZS; hop = 2; }
    else if (bid < 1536) { jt = 1; lb = bid - 1024; A = L3; Bt = Z + 3 * ZS; hop = 3; }
    else                 { jt = 2; int z = bid - 1536; hop = 4 + (z >> 9); lb = z & 511; }
  } else if constexpr (D == 4) {
    if (bid < 512)       { jt = 1; lb = bid;        A = L4; Bt = Z + 0 * ZS; hop = 4; }
    else if (bid < 1024) { jt = 1; lb = bid - 512;  A = L5; Bt = Z + 1 * ZS; hop = 5; }
    else                 { jt = 2; int z = bid - 1024; hop = 6;            lb = z; }
  } else {
    jt = 1; lb = bid; A = L6; Bt = Z + 2 * ZS; hop = 6;
  }

  if (jt == 2) {
    // ---- Z projection (K=192, direct-global) ----
    int b = lb >> 4, n0 = (lb & 15) * 128;
    const bf16_t* Wh = W1p + (size_t)hop * (NHID * 192);
    bf16_t* Zc = Z + (size_t)(hop & 3) * ZS;
    const bf16_t* arow[4];
    const bf16_t* brow[4];
#pragma unroll
    for (int mi = 0; mi < 4; ++mi)
      arow[mi] = Wh + (size_t)(wm * 64 + mi * 16 + l15) * 192 + quad * 8;
#pragma unroll
    for (int ni = 0; ni < 4; ++ni)
      brow[ni] = XT + (size_t)(n0 + wn * 64 + ni * 16 + l15) * NBW + b * NW + quad * 8;
    floatx4 zero4 = {0.f, 0.f, 0.f, 0.f};
    floatx4 acc[4][4];
#pragma unroll
    for (int mi = 0; mi < 4; ++mi)
#pragma unroll
      for (int ni = 0; ni < 4; ++ni) acc[mi][ni] = zero4;
#pragma unroll
    for (int kb = 0; kb < 192; kb += 32) {
      bf16x8 af[4], bf[4];
#pragma unroll
      for (int mi = 0; mi < 4; ++mi) af[mi] = *(const bf16x8*)(arow[mi] + kb);
#pragma unroll
      for (int ni = 0; ni < 4; ++ni) bf[ni] = *(const bf16x8*)(brow[ni] + kb);
#pragma unroll
      for (int mi = 0; mi < 4; ++mi)
#pragma unroll
        for (int ni = 0; ni < 4; ++ni)
          acc[mi][ni] =
              __builtin_amdgcn_mfma_f32_16x16x32_bf16(af[mi], bf[ni], acc[mi][ni], 0, 0, 0);
    }
#pragma unroll
    for (int mi = 0; mi < 4; ++mi) {
#pragma unroll
      for (int ni = 0; ni < 4; ++ni) {
        int col = n0 + wn * 64 + ni * 16 + l15;
        int rowb = b * 128 + wm * 64 + mi * 16 + quad * 4;
#pragma unroll
        for (int r = 0; r < 4; ++r)
          Zc[(size_t)(rowb + r) * 2048 + col] = (bf16_t)acc[mi][ni][r];
      }
    }
    return;
  }

  // ---- K=2048 NT GEMM (m97 BK=32 structure) ----
  int m0, nrow0, b = 0;
  if (jt == 0) {
    m0 = (lb >> 4) * 128;
    nrow0 = (lb & 15) * 128;
  } else {
    m0 = (lb >> 5) * 128;
    b = lb & 31;
    nrow0 = b * 128;
  }
  int p0 = wv * 128 + lane;
  int p1 = p0 + 64;
  int row0 = p0 >> 2, kc0 = (p0 & 3) ^ ((p0 >> 3) & 3);
  int row1 = p1 >> 2, kc1 = (p1 & 3) ^ ((p1 >> 3) & 3);
  const bf16_t* a0p = A + (size_t)(m0 + row0) * NM + kc0 * 8;
  const bf16_t* a1p = A + (size_t)(m0 + row1) * NM + kc1 * 8;
  const bf16_t* b0p = Bt + (size_t)(nrow0 + row0) * NM + kc0 * 8;
  const bf16_t* b1p = Bt + (size_t)(nrow0 + row1) * NM + kc1 * 8;
  bf16_t* As_d0 = As + (size_t)(wv * 128) * 8;
  bf16_t* As_d1 = As + (size_t)(wv * 128 + 64) * 8;
  bf16_t* Bs_d0 = Bs + (size_t)(wv * 128) * 8;
  bf16_t* Bs_d1 = Bs + (size_t)(wv * 128 + 64) * 8;
  int swz = (l15 >> 1) & 3;
  int kpos = (quad ^ swz) * 8;

  floatx4 zero4 = {0.f, 0.f, 0.f, 0.f};
  floatx4 acc[4][4];
#pragma unroll
  for (int mi = 0; mi < 4; ++mi)
#pragma unroll
    for (int ni = 0; ni < 4; ++ni) acc[mi][ni] = zero4;

  for (int kb = 0; kb < 2048; kb += 32) {
    GLOAD_LDS16(a0p + kb, As_d0);
    GLOAD_LDS16(a1p + kb, As_d1);
    GLOAD_LDS16(b0p + kb, Bs_d0);
    GLOAD_LDS16(b1p + kb, Bs_d1);
    __syncthreads();
    bf16x8 af[4], bf[4];
#pragma unroll
    for (int mi = 0; mi < 4; ++mi)
      af[mi] = *(const bf16x8*)(As + (wm * 64 + mi * 16 + l15) * 32 + kpos);
#pragma unroll
    for (int ni = 0; ni < 4; ++ni)
      bf[ni] = *(const bf16x8*)(Bs + (wn * 64 + ni * 16 + l15) * 32 + kpos);
#pragma unroll
    for (int mi = 0; mi < 4; ++mi)
#pragma unroll
      for (int ni = 0; ni < 4; ++ni)
        acc[mi][ni] = __builtin_amdgcn_mfma_f32_16x16x32_bf16(af[mi], bf[ni], acc[mi][ni], 0, 0, 0);
    __syncthreads();
  }

  if (jt == 0) {
#pragma unroll
    for (int mi = 0; mi < 4; ++mi) {
#pragma unroll
      for (int ni = 0; ni < 4; ++ni) {
        int col = nrow0 + wn * 64 + ni * 16 + l15;
        int rowb = m0 + wm * 64 + mi * 16 + quad * 4;
        bf16x4 tv;
#pragma unroll
        for (int r = 0; r < 4; ++r) tv[r] = (bf16_t)acc[mi][ni][r];
#pragma unroll
        for (int r = 0; r < 4; ++r) C[(size_t)(rowb + r) * NM + col] = tv[r];
        if (Ct) *(bf16x4*)(Ct + (size_t)col * NM + rowb) = tv;
      }
    }
  } else {
    // fused epilogue: per m-row, sum_h relu(acc + b1[hop,h]) * W2[hop,h]
    const float* b1h = b1 + hop * NHID;
    const float* w2h = W2 + hop * NHID;
    float part[4][4];
#pragma unroll
    for (int mi = 0; mi < 4; ++mi)
#pragma unroll
      for (int r = 0; r < 4; ++r) part[mi][r] = 0.f;
#pragma unroll
    for (int ni = 0; ni < 4; ++ni) {
      int h = wn * 64 + ni * 16 + l15;
      float b1v = b1h[h];
      float w2v = w2h[h];
#pragma unroll
      for (int mi = 0; mi < 4; ++mi)
#pragma unroll
        for (int r = 0; r < 4; ++r) {
          float hh = acc[mi][ni][r] + b1v;
          hh = hh > 0.f ? hh : 0.f;
          part[mi][r] += hh * w2v;
        }
    }
#pragma unroll
    for (int off = 1; off < 16; off <<= 1)
#pragma unroll
      for (int mi = 0; mi < 4; ++mi)
#pragma unroll
        for (int r = 0; r < 4; ++r) part[mi][r] += __shfl_xor(part[mi][r], off);
    if (l15 == 0) {
#pragma unroll
      for (int mi = 0; mi < 4; ++mi)
#pragma unroll
        for (int r = 0; r < 4; ++r) sred[wv][mi * 16 + quad * 4 + r] = part[mi][r];
    }
    __syncthreads();
    if (tid < 128) {
      int half = tid >> 6;
      int lr = tid & 63;
      float v = sred[half * 2][lr] + sred[half * 2 + 1][lr] + b2[hop];
      atomicAdd(out + (size_t)b * NM + m0 + half * 64 + lr, v);
    }
  }
}

extern "C" void kernel_launch(void* const* d_in, const int* in_sizes, int n_in,
                              void* d_out, int out_size, void* d_ws, size_t ws_size,
                              hipStream_t stream) {
  const float* x = (const float*)d_in[0];
  const float* L = (const float*)d_in[1];
  const float* W1 = (const float*)d_in[2];
  const float* b1 = (const float*)d_in[3];
  const float* W2 = (const float*)d_in[4];
  const float* b2 = (const float*)d_in[5];
  float* out = (float*)d_out;

  char* ws = (char*)d_ws;
  size_t off = 0;
  auto walloc = [&](size_t bytes) -> void* {
    off = (off + 255) & ~(size_t)255;
    void* p = ws + off;
    off += bytes;
    return p;
  };
  const size_t SZ_L = (size_t)NM * NM * 2;  // 8.39 MB
  bf16_t* W1p = (bf16_t*)walloc((size_t)7 * NHID * 192 * 2);
  bf16_t* XT = (bf16_t*)walloc((size_t)NM * NBW * 2);  // 22 MB
  bf16_t* Lb = (bf16_t*)walloc(SZ_L);
  bf16_t* Ltb = (bf16_t*)walloc(SZ_L);  // L^T; dead after D2 -> L5 overlays
  bf16_t* L2t = (bf16_t*)walloc(SZ_L);  // (L^2)^T; dead after D3
  bf16_t* L2 = (bf16_t*)walloc(SZ_L);
  bf16_t* L3 = (bf16_t*)walloc(SZ_L);
  bf16_t* L4 = (bf16_t*)walloc(SZ_L);
  bf16_t* L6 = (bf16_t*)walloc(SZ_L);
  bf16_t* L5 = Ltb;  // overlay: written D3, Ltb last read D2
  bf16_t* Z = (bf16_t*)walloc((size_t)4 * 4096 * 2048 * 2);  // ring-4, 67 MB
  walloc(4096);  // guard for Z-path A/B pad overreads
  (void)ws_size; (void)in_sizes; (void)n_in; (void)out_size;

  prep_all<<<dim3(3719), dim3(256), 0, stream>>>(x, XT, L, Lb, Ltb, W1, W1p);

  // D1: L^2 (+L2t) || Z0,Z1
  mega<1><<<dim3(1280), dim3(256), 0, stream>>>(XT, W1p, Lb, Ltb, L2t, L2, L3, L4, L5, L6, Z,
                                                b1, W2, b2, out);
  // hop 0 from Z0 (plain store, initializes all of out)
  score0<<<dim3(512), dim3(256), 0, stream>>>(Z, b1, W2, b2, out);
  // D2: L^3, L^4, H1 || Z2,Z3
  mega<2><<<dim3(2048), dim3(256), 0, stream>>>(XT, W1p, Lb, Ltb, L2t, L2, L3, L4, L5, L6, Z,
                                                b1, W2, b2, out);
  // D3: L^5, L^6, H2, H3 || Z4,Z5
  mega<3><<<dim3(2560), dim3(256), 0, stream>>>(XT, W1p, Lb, Ltb, L2t, L2, L3, L4, L5, L6, Z,
                                                b1, W2, b2, out);
  // D4: H4, H5 || Z6
  mega<4><<<dim3(1536), dim3(256), 0, stream>>>(XT, W1p, Lb, Ltb, L2t, L2, L3, L4, L5, L6, Z,
                                                b1, W2, b2, out);
  // D5: H6
  mega<5><<<dim3(512), dim3(256), 0, stream>>>(XT, W1p, Lb, Ltb, L2t, L2, L3, L4, L5, L6, Z,
                                               b1, W2, b2, out);
}